// Round 2
// baseline (571.826 us; speedup 1.0000x reference)
//
#include <hip/hip_runtime.h>
#include <stdint.h>

#define NR 16
#define NC 80
#define NA 8400
#define NB 16
#define KPRE 1024
#define MAXDET 300
#define CONF_T 0.25f
#define IOU_THR 0.45f
#define NBIN 65536

// Robust scalar read: harness passes python ints most likely as int32; fall
// back to float32 reinterpretation if the int pattern is implausible.
__device__ __forceinline__ float read_dim(const void* p) {
  int iv = *(const int*)p;
  return (iv > 0 && iv < (1 << 20)) ? (float)iv : *(const float*)p;
}

__device__ __forceinline__ const float* level_ptr(const float* p0, const float* p1,
                                                  const float* p2, int a, int& HW,
                                                  int& W, float& stride, int& m) {
  if (a < 6400)      { HW = 6400; W = 80; stride = 8.f;  m = a;        return p0; }
  else if (a < 8000) { HW = 1600; W = 40; stride = 16.f; m = a - 6400; return p1; }
  else               { HW = 400;  W = 20; stride = 32.f; m = a - 8000; return p2; }
}

// ----------------------------------------------------------------- zero -----
__global__ __launch_bounds__(256) void k_zero(uint4* __restrict__ hist4,
                                              int* __restrict__ ccount) {
  int t = blockIdx.x * 256 + threadIdx.x;
  if (t < NBIN * NB / 4) hist4[t] = make_uint4(0, 0, 0, 0);
  if (t < NB) ccount[t] = 0;
}

// ---------------------------------------------------------------- decode ----
// Class argmax + sortable key + key histogram. (DFL box decode deferred to
// k_rank2 — only the 1024 winners per image need boxes.)
__global__ __launch_bounds__(256) void k_decode(
    const float* __restrict__ p0, const float* __restrict__ p1,
    const float* __restrict__ p2, uint32_t* __restrict__ keys,
    int* __restrict__ labels, uint32_t* __restrict__ hist) {
  int gid = blockIdx.x * 256 + threadIdx.x;
  if (gid >= NB * NA) return;
  int b = gid / NA, a = gid - b * NA;
  int HW, W, m; float stride;
  const float* p = level_ptr(p0, p1, p2, a, HW, W, stride, m);
  const float* cls = p + (size_t)b * (4 * NR + NC) * HW + (size_t)(4 * NR) * HW + m;

  // class max / argmax on raw logits (sigmoid monotone; strict > = first idx)
  float ml = cls[0]; int mc = 0;
#pragma unroll 4
  for (int c = 1; c < NC; ++c) {
    float v = cls[(size_t)c * HW];
    if (v > ml) { ml = v; mc = c; }
  }
  labels[gid] = mc;
  float smax = 1.f / (1.f + expf(-ml));
  float s = smax > CONF_T ? smax : -1.0f;
  uint32_t bt = __float_as_uint(s);
  uint32_t key = (bt & 0x80000000u) ? ~bt : (bt | 0x80000000u);  // order-preserving
  keys[gid] = key;
  atomicAdd(&hist[b * NBIN + (key >> 16)], 1u);
}

// ------------------------------------------------------- threshold select ---
// t*[img] = max bin t such that count(bin >= t) >= KPRE.
__global__ __launch_bounds__(256) void k_thresh(const uint32_t* __restrict__ hist,
                                                int* __restrict__ tstar) {
  __shared__ uint32_t lsum[256];
  int img = blockIdx.x;
  const uint32_t* h = hist + (size_t)img * NBIN;
  int i = threadIdx.x;
  int lo = i * (NBIN / 256), hi = lo + (NBIN / 256);
  uint32_t L = 0;
  for (int b = lo; b < hi; ++b) L += h[b];
  lsum[i] = L;
  __syncthreads();
  uint32_t H = 0;  // suffix count of higher bins
  for (int j = i + 1; j < 256; ++j) H += lsum[j];
  if (H < KPRE && H + L >= KPRE) {
    uint32_t run = H;
    for (int b = hi - 1; b >= lo; --b) {
      run += h[b];
      if (run >= KPRE) { tstar[img] = b; break; }
    }
  }
  if (i == 0 && H + L < KPRE) tstar[img] = 0;  // degenerate: fewer than KPRE total
}

// --------------------------------------------------------------- compact ----
__global__ __launch_bounds__(256) void k_compact(const uint32_t* __restrict__ keys,
                                                 const int* __restrict__ tstar,
                                                 uint64_t* __restrict__ cmp,
                                                 int* __restrict__ ccount) {
  int gid = blockIdx.x * 256 + threadIdx.x;
  if (gid >= NB * NA) return;
  int b = gid / NA, a = gid - b * NA;
  uint32_t key = keys[gid];
  if ((int)(key >> 16) >= tstar[b]) {
    int slot = atomicAdd(&ccount[b], 1);
    cmp[(size_t)b * NA + slot] =
        ((uint64_t)key << 32) | (uint64_t)(0xFFFFFFFFu - (uint32_t)a);
  }
}

// ------------------------------------------------- exact rank on top-M set --
// Compacted set == exact top-M keys (upward-closed at bin granularity), so
// local rank == global rank. Winners (rank < KPRE) also recompute their DFL
// box here (only 16K boxes instead of 134K).
__global__ __launch_bounds__(256) void k_rank2(
    const uint64_t* __restrict__ cmp, const int* __restrict__ ccount,
    const float* __restrict__ p0, const float* __restrict__ p1,
    const float* __restrict__ p2, const int* __restrict__ labels,
    const void* __restrict__ hp, const void* __restrict__ wp,
    float4* __restrict__ selbox, float4* __restrict__ selboff,
    float* __restrict__ selscore, int* __restrict__ sellab) {
  __shared__ uint64_t sk[2048];
  int img = blockIdx.y;
  int M = ccount[img]; if (M > NA) M = NA;
  if (blockIdx.x * 256 >= M) return;  // uniform per block
  int c = blockIdx.x * 256 + threadIdx.x;
  uint64_t kc = (c < M) ? cmp[(size_t)img * NA + c] : 0;
  int rank = 0;
  for (int j0 = 0; j0 < M; j0 += 2048) {
    int nchunk = min(2048, M - j0);
    __syncthreads();
    for (int j = threadIdx.x; j < nchunk; j += 256)
      sk[j] = cmp[(size_t)img * NA + j0 + j];
    __syncthreads();
    if (c < M) {
      int j = 0;
      for (; j + 4 <= nchunk; j += 4) {
        rank += (int)(sk[j] > kc) + (int)(sk[j + 1] > kc) +
                (int)(sk[j + 2] > kc) + (int)(sk[j + 3] > kc);
      }
      for (; j < nchunk; ++j) rank += (int)(sk[j] > kc);
    }
  }
  if (c < M && rank < KPRE) {
    int a = (int)(0xFFFFFFFFu - (uint32_t)kc);
    uint32_t uk = (uint32_t)(kc >> 32);
    uint32_t bits = (uk & 0x80000000u) ? (uk & 0x7FFFFFFFu) : ~uk;
    float s = __uint_as_float(bits);
    int lab = labels[img * NA + a];

    // DFL box decode for this anchor
    int HW, W, m; float stride;
    const float* p = level_ptr(p0, p1, p2, a, HW, W, stride, m);
    const float* base = p + (size_t)img * (4 * NR + NC) * HW + m;
    float d[4];
#pragma unroll
    for (int k = 0; k < 4; ++k) {
      float v[NR]; float mx = -3.4e38f;
#pragma unroll
      for (int r = 0; r < NR; ++r) { v[r] = base[(size_t)(k * NR + r) * HW]; mx = fmaxf(mx, v[r]); }
      float se = 0.f, sn = 0.f;
#pragma unroll
      for (int r = 0; r < NR; ++r) { float e = expf(v[r] - mx); se += e; sn += e * (float)r; }
      d[k] = sn / se * stride;
    }
    int x = m % W, y = m / W;
    float cx = ((float)x + 0.5f) * stride, cy = ((float)y + 0.5f) * stride;
    float hx = read_dim(wp) - 1.f, hy = read_dim(hp) - 1.f;
    float4 bx = make_float4(fminf(fmaxf(cx - d[0], 0.f), hx),
                            fminf(fmaxf(cy - d[1], 0.f), hy),
                            fminf(fmaxf(cx + d[2], 0.f), hx),
                            fminf(fmaxf(cy + d[3], 0.f), hy));
    float off = (float)lab * 4096.0f;  // replicate reference CLS_OFFSET fp math
    int o = img * KPRE + rank;
    selbox[o] = bx;
    selboff[o] = make_float4(bx.x + off, bx.y + off, bx.z + off, bx.w + off);
    selscore[o] = s;
    sellab[o] = lab;
  }
}

// ----------------------------------------------------- IoU suppression bits -
__global__ __launch_bounds__(256) void k_iou(const float4* __restrict__ selboff,
                                             uint64_t* __restrict__ rowmask) {
  __shared__ float4 bb[KPRE];
  int img = blockIdx.y;
  for (int j = threadIdx.x; j < KPRE; j += 256) bb[j] = selboff[img * KPRE + j];
  __syncthreads();
  int i = blockIdx.x * 16 + (threadIdx.x >> 4);
  int w = threadIdx.x & 15;
  float4 bi = bb[i];
  float ai = (bi.z - bi.x) * (bi.w - bi.y);
  uint64_t bits = 0;
  for (int jj = 0; jj < 64; ++jj) {
    int j = w * 64 + jj;
    float4 bj = bb[j];
    float lx = fmaxf(bi.x, bj.x), ly = fmaxf(bi.y, bj.y);
    float rx = fminf(bi.z, bj.z), ry = fminf(bi.w, bj.w);
    float iw = fmaxf(rx - lx, 0.f), ih = fmaxf(ry - ly, 0.f);
    float inter = iw * ih;
    float aj = (bj.z - bj.x) * (bj.w - bj.y);
    float iou = inter / (ai + aj - inter + 1e-7f);
    bits |= (uint64_t)((iou > IOU_THR) && (j != i)) << jj;
  }
  rowmask[(size_t)(img * KPRE + i) * 16 + w] = bits;
}

// ------------------------------------------------------ serial greedy scan --
__global__ __launch_bounds__(64) void k_scan(
    const uint64_t* __restrict__ rowmask, const float* __restrict__ selbox_f,
    const float* __restrict__ selscore, const int* __restrict__ sellab,
    float* __restrict__ out) {
  __shared__ float lsc[KPRE];
  __shared__ uint64_t rows[64 * 16];
  int img = blockIdx.x;
  int lane = threadIdx.x;
  for (int j = lane; j < KPRE; j += 64) lsc[j] = selscore[img * KPRE + j];
  __syncthreads();

  float* ob = out;                        // (B,300,4)
  float* os = out + NB * MAXDET * 4;      // (B,300)
  float* ol = out + NB * MAXDET * 5;      // (B,300) labels as float
  float* ov = out + NB * MAXDET * 6;      // (B,300) valid as 0/1 float

  uint64_t remv = 0;  // lane t<16 owns 64-bit word t of the 1024-bit mask
  int n = 0;
  for (int chunk = 0; chunk < 16 && n < MAXDET; ++chunk) {
    const uint64_t* g = rowmask + (size_t)(img * KPRE + chunk * 64) * 16;
    for (int k2 = lane; k2 < 1024; k2 += 64) rows[k2] = g[k2];
    __syncthreads();
    for (int ii = 0; ii < 64; ++ii) {
      int i = chunk * 64 + ii;
      int supbit = (int)((remv >> ii) & 1ull);
      supbit = __shfl(supbit, chunk);  // word index of bit i is exactly `chunk`
      if (!supbit && lsc[i] > CONF_T) {
        remv |= (lane < 16) ? rows[ii * 16 + lane] : 0ull;
        if (lane < 4)       ob[(size_t)(img * MAXDET + n) * 4 + lane] =
                                selbox_f[(size_t)(img * KPRE + i) * 4 + lane];
        else if (lane == 4) os[img * MAXDET + n] = lsc[i];
        else if (lane == 5) ol[img * MAXDET + n] = (float)sellab[img * KPRE + i];
        n++;
        if (n == MAXDET) break;
      }
    }
    __syncthreads();
  }
  for (int slot = lane; slot < MAXDET; slot += 64) {
    ov[img * MAXDET + slot] = (slot < n) ? 1.0f : 0.0f;
    if (slot >= n) {
      os[img * MAXDET + slot] = 0.0f;
      ol[img * MAXDET + slot] = -1.0f;
      float* bp = ob + (size_t)(img * MAXDET + slot) * 4;
      bp[0] = 0.f; bp[1] = 0.f; bp[2] = 0.f; bp[3] = 0.f;
    }
  }
}

// -------------------------------------------------------------- launcher ----
extern "C" void kernel_launch(void* const* d_in, const int* in_sizes, int n_in,
                              void* d_out, int out_size, void* d_ws, size_t ws_size,
                              hipStream_t stream) {
  const float* p0 = (const float*)d_in[0];
  const float* p1 = (const float*)d_in[1];
  const float* p2 = (const float*)d_in[2];
  const void* hp = d_in[3];
  const void* wp = d_in[4];

  // Workspace layout (total 5,924,992 B; hist region aliased by compact and
  // rowmask, which are only written after the last hist read in k_thresh).
  char* ws = (char*)d_ws;
  uint32_t* keys     = (uint32_t*)(ws + 0);        // 537600
  int*      labels   = (int*)(ws + 537600);        // 537600
  float4*   selbox   = (float4*)(ws + 1075200);    // 262144
  float4*   selboff  = (float4*)(ws + 1337344);    // 262144
  float*    selscore = (float*)(ws + 1599488);     // 65536
  int*      sellab   = (int*)(ws + 1665024);       // 65536
  int*      ccount   = (int*)(ws + 1730560);       // 64
  int*      tstar    = (int*)(ws + 1730624);       // 64
  uint32_t* hist     = (uint32_t*)(ws + 1730688);  // 4194304 (dead after k_thresh)
  uint64_t* cmp      = (uint64_t*)(ws + 1730688);            // alias: 1075200
  uint64_t* rowmask  = (uint64_t*)(ws + 1730688 + 1075200);  // alias: 2097152

  k_zero<<<1024, 256, 0, stream>>>((uint4*)hist, ccount);
  k_decode<<<(NB * NA + 255) / 256, 256, 0, stream>>>(p0, p1, p2, keys, labels, hist);
  k_thresh<<<NB, 256, 0, stream>>>(hist, tstar);
  k_compact<<<(NB * NA + 255) / 256, 256, 0, stream>>>(keys, tstar, cmp, ccount);
  dim3 rg((NA + 255) / 256, NB);
  k_rank2<<<rg, 256, 0, stream>>>(cmp, ccount, p0, p1, p2, labels, hp, wp,
                                  selbox, selboff, selscore, sellab);
  dim3 ig(KPRE / 16, NB);
  k_iou<<<ig, 256, 0, stream>>>(selboff, rowmask);
  k_scan<<<NB, 64, 0, stream>>>(rowmask, (const float*)selbox, selscore,
                                sellab, (float*)d_out);
}

// Round 3
// 342.331 us; speedup vs baseline: 1.6704x; 1.6704x over previous
//
#include <hip/hip_runtime.h>
#include <stdint.h>

#define NR 16
#define NC 80
#define NA 8400
#define NB 16
#define KPRE 1024
#define MAXDET 300
#define CONF_T 0.25f
#define IOU_THR 0.45f

// Robust scalar read: harness passes python ints most likely as int32; fall
// back to float32 reinterpretation if the int pattern is implausible.
__device__ __forceinline__ float read_dim(const void* p) {
  int iv = *(const int*)p;
  return (iv > 0 && iv < (1 << 20)) ? (float)iv : *(const float*)p;
}

__device__ __forceinline__ const float* level_ptr(const float* p0, const float* p1,
                                                  const float* p2, int a, int& HW,
                                                  int& W, float& stride, int& m) {
  if (a < 6400)      { HW = 6400; W = 80; stride = 8.f;  m = a;        return p0; }
  else if (a < 8000) { HW = 1600; W = 40; stride = 16.f; m = a - 6400; return p1; }
  else               { HW = 400;  W = 20; stride = 32.f; m = a - 8000; return p2; }
}

// ---------------------------------------------------------------- decode ----
// Class argmax + sortable key only. No histogram (global atomics on hot bins
// serialized ~100+us in R2). Box decode deferred to k_rank2 (winners only).
__global__ __launch_bounds__(256) void k_decode(
    const float* __restrict__ p0, const float* __restrict__ p1,
    const float* __restrict__ p2, uint32_t* __restrict__ keys,
    int* __restrict__ labels) {
  int gid = blockIdx.x * 256 + threadIdx.x;
  if (gid >= NB * NA) return;
  int b = gid / NA, a = gid - b * NA;
  int HW, W, m; float stride;
  const float* p = level_ptr(p0, p1, p2, a, HW, W, stride, m);
  const float* cls = p + (size_t)b * (4 * NR + NC) * HW + (size_t)(4 * NR) * HW + m;

  // class max / argmax on raw logits (sigmoid monotone; strict > = first idx)
  float ml = cls[0]; int mc = 0;
#pragma unroll 4
  for (int c = 1; c < NC; ++c) {
    float v = cls[(size_t)c * HW];
    if (v > ml) { ml = v; mc = c; }
  }
  labels[gid] = mc;
  float smax = 1.f / (1.f + expf(-ml));
  float s = smax > CONF_T ? smax : -1.0f;
  uint32_t bt = __float_as_uint(s);
  keys[gid] = (bt & 0x80000000u) ? ~bt : (bt | 0x80000000u);  // order-preserving
}

// ------------------------------------------- per-image LDS radix threshold --
// One block per image. Finds t16 = largest 16-bit value such that
// count(key>>16 >= t16) >= KPRE, via two 8-bit radix passes with per-wave
// LDS histograms (no global atomics; LDS contention bounded per wave).
__global__ __launch_bounds__(1024) void k_select(const uint32_t* __restrict__ keys,
                                                 int* __restrict__ tstar,
                                                 int* __restrict__ ccount) {
  __shared__ uint32_t skeys[NA];       // 33600 B
  __shared__ uint32_t whist[16][256];  // 16 KB, one hist per wave
  __shared__ uint32_t hsum[256];
  __shared__ uint32_t ssuf[256];
  __shared__ int s_b1, s_rem;
  int img = blockIdx.x;
  int tid = threadIdx.x;
  int w = tid >> 6;
  const uint32_t* kb = keys + (size_t)img * NA;
  for (int j = tid; j < NA; j += 1024) skeys[j] = kb[j];
  if (tid == 0) ccount[img] = 0;  // consumed by k_compact later in-stream

  // ---- pass 1: digit = key >> 24 ----
  for (int j = tid; j < 16 * 256; j += 1024) ((uint32_t*)whist)[j] = 0;
  __syncthreads();
  for (int j = tid; j < NA; j += 1024) atomicAdd(&whist[w][skeys[j] >> 24], 1u);
  __syncthreads();
  if (tid < 256) {
    uint32_t s = 0;
    for (int i = 0; i < 16; ++i) s += whist[i][tid];
    hsum[tid] = s;
  }
  __syncthreads();
  if (tid < 256) {
    uint32_t s = 0;
    for (int j = tid; j < 256; ++j) s += hsum[j];
    ssuf[tid] = s;  // inclusive suffix count
  }
  __syncthreads();
  if (tid < 256) {
    uint32_t above = (tid == 255) ? 0u : ssuf[tid + 1];
    if (ssuf[tid] >= KPRE && above < KPRE) { s_b1 = tid; s_rem = KPRE - (int)above; }
  }
  __syncthreads();
  int b1 = s_b1, rem = s_rem;

  // ---- pass 2: digit = (key>>16)&0xFF restricted to (key>>24)==b1 ----
  __syncthreads();
  for (int j = tid; j < 16 * 256; j += 1024) ((uint32_t*)whist)[j] = 0;
  __syncthreads();
  for (int j = tid; j < NA; j += 1024) {
    uint32_t k = skeys[j];
    if ((int)(k >> 24) == b1) atomicAdd(&whist[w][(k >> 16) & 0xFF], 1u);
  }
  __syncthreads();
  if (tid < 256) {
    uint32_t s = 0;
    for (int i = 0; i < 16; ++i) s += whist[i][tid];
    hsum[tid] = s;
  }
  __syncthreads();
  if (tid < 256) {
    uint32_t s = 0;
    for (int j = tid; j < 256; ++j) s += hsum[j];
    ssuf[tid] = s;
  }
  __syncthreads();
  if (tid < 256) {
    uint32_t above = (tid == 255) ? 0u : ssuf[tid + 1];
    if ((int)ssuf[tid] >= rem && (int)above < rem) tstar[img] = (b1 << 8) | tid;
  }
}

// --------------------------------------------------------------- compact ----
// Block-aggregated slot assignment: one global atomic per block (528 total)
// instead of one per passing thread (~17.6K serialized on one line in R2).
// Order inside cmp is irrelevant: k_rank2 computes exact ranks from keys.
__global__ __launch_bounds__(256) void k_compact(const uint32_t* __restrict__ keys,
                                                 const int* __restrict__ tstar,
                                                 uint64_t* __restrict__ cmp,
                                                 int* __restrict__ ccount) {
  __shared__ int wcnt[4];
  __shared__ int sbase;
  int img = blockIdx.y;
  int a = blockIdx.x * 256 + threadIdx.x;
  int lane = threadIdx.x & 63, w = threadIdx.x >> 6;
  uint32_t key = 0; bool pass = false;
  if (a < NA) {
    key = keys[(size_t)img * NA + a];
    pass = (int)(key >> 16) >= tstar[img];
  }
  uint64_t mask = __ballot(pass);
  int pre = __popcll(mask & ((1ull << lane) - 1ull));
  if (lane == 0) wcnt[w] = __popcll(mask);
  __syncthreads();
  if (threadIdx.x == 0) {
    int tot = wcnt[0] + wcnt[1] + wcnt[2] + wcnt[3];
    sbase = tot ? atomicAdd(&ccount[img], tot) : 0;
  }
  __syncthreads();
  if (pass) {
    int off = sbase + pre;
    for (int i = 0; i < w; ++i) off += wcnt[i];
    cmp[(size_t)img * NA + off] =
        ((uint64_t)key << 32) | (uint64_t)(0xFFFFFFFFu - (uint32_t)a);
  }
}

// ------------------------------------------------- exact rank on top-M set --
// Compacted set == exact top-M keys (upward-closed at bin granularity), so
// local rank == global rank. Winners (rank < KPRE) also recompute their DFL
// box here (only 16K boxes instead of 134K).
__global__ __launch_bounds__(256) void k_rank2(
    const uint64_t* __restrict__ cmp, const int* __restrict__ ccount,
    const float* __restrict__ p0, const float* __restrict__ p1,
    const float* __restrict__ p2, const int* __restrict__ labels,
    const void* __restrict__ hp, const void* __restrict__ wp,
    float4* __restrict__ selbox, float4* __restrict__ selboff,
    float* __restrict__ selscore, int* __restrict__ sellab) {
  __shared__ uint64_t sk[2048];
  int img = blockIdx.y;
  int M = ccount[img]; if (M > NA) M = NA;
  if (blockIdx.x * 256 >= M) return;  // uniform per block
  int c = blockIdx.x * 256 + threadIdx.x;
  uint64_t kc = (c < M) ? cmp[(size_t)img * NA + c] : 0;
  int rank = 0;
  for (int j0 = 0; j0 < M; j0 += 2048) {
    int nchunk = min(2048, M - j0);
    __syncthreads();
    for (int j = threadIdx.x; j < nchunk; j += 256)
      sk[j] = cmp[(size_t)img * NA + j0 + j];
    __syncthreads();
    if (c < M) {
      int j = 0;
      for (; j + 4 <= nchunk; j += 4) {
        rank += (int)(sk[j] > kc) + (int)(sk[j + 1] > kc) +
                (int)(sk[j + 2] > kc) + (int)(sk[j + 3] > kc);
      }
      for (; j < nchunk; ++j) rank += (int)(sk[j] > kc);
    }
  }
  if (c < M && rank < KPRE) {
    int a = (int)(0xFFFFFFFFu - (uint32_t)kc);
    uint32_t uk = (uint32_t)(kc >> 32);
    uint32_t bits = (uk & 0x80000000u) ? (uk & 0x7FFFFFFFu) : ~uk;
    float s = __uint_as_float(bits);
    int lab = labels[img * NA + a];

    // DFL box decode for this anchor
    int HW, W, m; float stride;
    const float* p = level_ptr(p0, p1, p2, a, HW, W, stride, m);
    const float* base = p + (size_t)img * (4 * NR + NC) * HW + m;
    float d[4];
#pragma unroll
    for (int k = 0; k < 4; ++k) {
      float v[NR]; float mx = -3.4e38f;
#pragma unroll
      for (int r = 0; r < NR; ++r) { v[r] = base[(size_t)(k * NR + r) * HW]; mx = fmaxf(mx, v[r]); }
      float se = 0.f, sn = 0.f;
#pragma unroll
      for (int r = 0; r < NR; ++r) { float e = expf(v[r] - mx); se += e; sn += e * (float)r; }
      d[k] = sn / se * stride;
    }
    int x = m % W, y = m / W;
    float cx = ((float)x + 0.5f) * stride, cy = ((float)y + 0.5f) * stride;
    float hx = read_dim(wp) - 1.f, hy = read_dim(hp) - 1.f;
    float4 bx = make_float4(fminf(fmaxf(cx - d[0], 0.f), hx),
                            fminf(fmaxf(cy - d[1], 0.f), hy),
                            fminf(fmaxf(cx + d[2], 0.f), hx),
                            fminf(fmaxf(cy + d[3], 0.f), hy));
    float off = (float)lab * 4096.0f;  // replicate reference CLS_OFFSET fp math
    int o = img * KPRE + rank;
    selbox[o] = bx;
    selboff[o] = make_float4(bx.x + off, bx.y + off, bx.z + off, bx.w + off);
    selscore[o] = s;
    sellab[o] = lab;
  }
}

// ----------------------------------------------------- IoU suppression bits -
__global__ __launch_bounds__(256) void k_iou(const float4* __restrict__ selboff,
                                             uint64_t* __restrict__ rowmask) {
  __shared__ float4 bb[KPRE];
  int img = blockIdx.y;
  for (int j = threadIdx.x; j < KPRE; j += 256) bb[j] = selboff[img * KPRE + j];
  __syncthreads();
  int i = blockIdx.x * 16 + (threadIdx.x >> 4);
  int w = threadIdx.x & 15;
  float4 bi = bb[i];
  float ai = (bi.z - bi.x) * (bi.w - bi.y);
  uint64_t bits = 0;
  for (int jj = 0; jj < 64; ++jj) {
    int j = w * 64 + jj;
    float4 bj = bb[j];
    float lx = fmaxf(bi.x, bj.x), ly = fmaxf(bi.y, bj.y);
    float rx = fminf(bi.z, bj.z), ry = fminf(bi.w, bj.w);
    float iw = fmaxf(rx - lx, 0.f), ih = fmaxf(ry - ly, 0.f);
    float inter = iw * ih;
    float aj = (bj.z - bj.x) * (bj.w - bj.y);
    float iou = inter / (ai + aj - inter + 1e-7f);
    bits |= (uint64_t)((iou > IOU_THR) && (j != i)) << jj;
  }
  rowmask[(size_t)(img * KPRE + i) * 16 + w] = bits;
}

// ------------------------------------------------------ serial greedy scan --
__global__ __launch_bounds__(64) void k_scan(
    const uint64_t* __restrict__ rowmask, const float* __restrict__ selbox_f,
    const float* __restrict__ selscore, const int* __restrict__ sellab,
    float* __restrict__ out) {
  __shared__ float lsc[KPRE];
  __shared__ uint64_t rows[64 * 16];
  int img = blockIdx.x;
  int lane = threadIdx.x;
  for (int j = lane; j < KPRE; j += 64) lsc[j] = selscore[img * KPRE + j];
  __syncthreads();

  float* ob = out;                        // (B,300,4)
  float* os = out + NB * MAXDET * 4;      // (B,300)
  float* ol = out + NB * MAXDET * 5;      // (B,300) labels as float
  float* ov = out + NB * MAXDET * 6;      // (B,300) valid as 0/1 float

  uint64_t remv = 0;  // lane t<16 owns 64-bit word t of the 1024-bit mask
  int n = 0;
  for (int chunk = 0; chunk < 16 && n < MAXDET; ++chunk) {
    const uint64_t* g = rowmask + (size_t)(img * KPRE + chunk * 64) * 16;
    for (int k2 = lane; k2 < 1024; k2 += 64) rows[k2] = g[k2];
    __syncthreads();
    for (int ii = 0; ii < 64; ++ii) {
      int i = chunk * 64 + ii;
      int supbit = (int)((remv >> ii) & 1ull);
      supbit = __shfl(supbit, chunk);  // word index of bit i is exactly `chunk`
      if (!supbit && lsc[i] > CONF_T) {
        remv |= (lane < 16) ? rows[ii * 16 + lane] : 0ull;
        if (lane < 4)       ob[(size_t)(img * MAXDET + n) * 4 + lane] =
                                selbox_f[(size_t)(img * KPRE + i) * 4 + lane];
        else if (lane == 4) os[img * MAXDET + n] = lsc[i];
        else if (lane == 5) ol[img * MAXDET + n] = (float)sellab[img * KPRE + i];
        n++;
        if (n == MAXDET) break;
      }
    }
    __syncthreads();
  }
  for (int slot = lane; slot < MAXDET; slot += 64) {
    ov[img * MAXDET + slot] = (slot < n) ? 1.0f : 0.0f;
    if (slot >= n) {
      os[img * MAXDET + slot] = 0.0f;
      ol[img * MAXDET + slot] = -1.0f;
      float* bp = ob + (size_t)(img * MAXDET + slot) * 4;
      bp[0] = 0.f; bp[1] = 0.f; bp[2] = 0.f; bp[3] = 0.f;
    }
  }
}

// -------------------------------------------------------------- launcher ----
extern "C" void kernel_launch(void* const* d_in, const int* in_sizes, int n_in,
                              void* d_out, int out_size, void* d_ws, size_t ws_size,
                              hipStream_t stream) {
  const float* p0 = (const float*)d_in[0];
  const float* p1 = (const float*)d_in[1];
  const float* p2 = (const float*)d_in[2];
  const void* hp = d_in[3];
  const void* wp = d_in[4];

  // Workspace layout (total ~4.9 MB)
  char* ws = (char*)d_ws;
  uint32_t* keys     = (uint32_t*)(ws + 0);        // 537600
  int*      labels   = (int*)(ws + 537600);        // 537600
  float4*   selbox   = (float4*)(ws + 1075200);    // 262144
  float4*   selboff  = (float4*)(ws + 1337344);    // 262144
  float*    selscore = (float*)(ws + 1599488);     // 65536
  int*      sellab   = (int*)(ws + 1665024);       // 65536
  int*      ccount   = (int*)(ws + 1730560);       // 64
  int*      tstar    = (int*)(ws + 1730624);       // 64
  uint64_t* cmp      = (uint64_t*)(ws + 1730688);  // 1075200
  uint64_t* rowmask  = (uint64_t*)(ws + 2805888);  // 2097152

  k_decode<<<(NB * NA + 255) / 256, 256, 0, stream>>>(p0, p1, p2, keys, labels);
  k_select<<<NB, 1024, 0, stream>>>(keys, tstar, ccount);
  dim3 cg((NA + 255) / 256, NB);
  k_compact<<<cg, 256, 0, stream>>>(keys, tstar, cmp, ccount);
  dim3 rg((NA + 255) / 256, NB);
  k_rank2<<<rg, 256, 0, stream>>>(cmp, ccount, p0, p1, p2, labels, hp, wp,
                                  selbox, selboff, selscore, sellab);
  dim3 ig(KPRE / 16, NB);
  k_iou<<<ig, 256, 0, stream>>>(selboff, rowmask);
  k_scan<<<NB, 64, 0, stream>>>(rowmask, (const float*)selbox, selscore,
                                sellab, (float*)d_out);
}

// Round 4
// 225.458 us; speedup vs baseline: 2.5363x; 1.5184x over previous
//
#include <hip/hip_runtime.h>
#include <stdint.h>

#define NR 16
#define NC 80
#define NA 8400
#define NB 16
#define KPRE 1024
#define MAXDET 300
#define CONF_T 0.25f
#define IOU_THR 0.45f

// Robust scalar read: harness passes python ints most likely as int32; fall
// back to float32 reinterpretation if the int pattern is implausible.
__device__ __forceinline__ float read_dim(const void* p) {
  int iv = *(const int*)p;
  return (iv > 0 && iv < (1 << 20)) ? (float)iv : *(const float*)p;
}

__device__ __forceinline__ const float* level_ptr(const float* p0, const float* p1,
                                                  const float* p2, int a, int& HW,
                                                  int& W, float& stride, int& m) {
  if (a < 6400)      { HW = 6400; W = 80; stride = 8.f;  m = a;        return p0; }
  else if (a < 8000) { HW = 1600; W = 40; stride = 16.f; m = a - 6400; return p1; }
  else               { HW = 400;  W = 20; stride = 32.f; m = a - 8000; return p2; }
}

__device__ __forceinline__ uint64_t readlane64(uint64_t v, int lane) {
  uint32_t lo = (uint32_t)__builtin_amdgcn_readlane((int)(uint32_t)v, lane);
  uint32_t hi = (uint32_t)__builtin_amdgcn_readlane((int)(uint32_t)(v >> 32), lane);
  return ((uint64_t)hi << 32) | lo;
}

// ---------------------------------------------------------------- decode ----
__global__ __launch_bounds__(256) void k_decode(
    const float* __restrict__ p0, const float* __restrict__ p1,
    const float* __restrict__ p2, uint32_t* __restrict__ keys,
    int* __restrict__ labels) {
  int gid = blockIdx.x * 256 + threadIdx.x;
  if (gid >= NB * NA) return;
  int b = gid / NA, a = gid - b * NA;
  int HW, W, m; float stride;
  const float* p = level_ptr(p0, p1, p2, a, HW, W, stride, m);
  const float* cls = p + (size_t)b * (4 * NR + NC) * HW + (size_t)(4 * NR) * HW + m;

  float ml = cls[0]; int mc = 0;
#pragma unroll 4
  for (int c = 1; c < NC; ++c) {
    float v = cls[(size_t)c * HW];
    if (v > ml) { ml = v; mc = c; }
  }
  labels[gid] = mc;
  float smax = 1.f / (1.f + expf(-ml));
  float s = smax > CONF_T ? smax : -1.0f;
  uint32_t bt = __float_as_uint(s);
  keys[gid] = (bt & 0x80000000u) ? ~bt : (bt | 0x80000000u);  // order-preserving
}

// ------------------------------- fused radix threshold + compact (per img) --
__global__ __launch_bounds__(1024) void k_selcomp(const uint32_t* __restrict__ keys,
                                                  uint64_t* __restrict__ cmp,
                                                  int* __restrict__ ccount) {
  __shared__ uint32_t skeys[NA];       // 33600 B
  __shared__ uint32_t whist[16][256];  // 16 KB, one hist per wave
  __shared__ uint32_t hsum[256];
  __shared__ uint32_t ssuf[256];
  __shared__ int s_b1, s_rem, s_t16, s_cnt;
  int img = blockIdx.x;
  int tid = threadIdx.x;
  int w = tid >> 6, lane = tid & 63;
  const uint32_t* kb = keys + (size_t)img * NA;
  for (int j = tid; j < NA; j += 1024) skeys[j] = kb[j];
  if (tid == 0) s_cnt = 0;

  // ---- pass 1: digit = key >> 24 ----
  for (int j = tid; j < 16 * 256; j += 1024) ((uint32_t*)whist)[j] = 0;
  __syncthreads();
  for (int j = tid; j < NA; j += 1024) atomicAdd(&whist[w][skeys[j] >> 24], 1u);
  __syncthreads();
  if (tid < 256) { uint32_t s = 0; for (int i = 0; i < 16; ++i) s += whist[i][tid]; hsum[tid] = s; }
  __syncthreads();
  if (tid < 256) { uint32_t s = 0; for (int j = tid; j < 256; ++j) s += hsum[j]; ssuf[tid] = s; }
  __syncthreads();
  if (tid < 256) {
    uint32_t ab = (tid == 255) ? 0u : ssuf[tid + 1];
    if (ssuf[tid] >= KPRE && ab < KPRE) { s_b1 = tid; s_rem = KPRE - (int)ab; }
  }
  __syncthreads();
  int b1 = s_b1, rem = s_rem;
  __syncthreads();

  // ---- pass 2: digit = (key>>16)&0xFF restricted to (key>>24)==b1 ----
  for (int j = tid; j < 16 * 256; j += 1024) ((uint32_t*)whist)[j] = 0;
  __syncthreads();
  for (int j = tid; j < NA; j += 1024) {
    uint32_t k = skeys[j];
    if ((int)(k >> 24) == b1) atomicAdd(&whist[w][(k >> 16) & 0xFF], 1u);
  }
  __syncthreads();
  if (tid < 256) { uint32_t s = 0; for (int i = 0; i < 16; ++i) s += whist[i][tid]; hsum[tid] = s; }
  __syncthreads();
  if (tid < 256) { uint32_t s = 0; for (int j = tid; j < 256; ++j) s += hsum[j]; ssuf[tid] = s; }
  __syncthreads();
  if (tid < 256) {
    int ab = (tid == 255) ? 0 : (int)ssuf[tid + 1];
    if ((int)ssuf[tid] >= rem && ab < rem) s_t16 = (b1 << 8) | tid;
  }
  __syncthreads();
  uint32_t t16 = (uint32_t)s_t16;

  // ---- compact: wave-aggregated slot assignment via one LDS atomic/wave ----
  for (int j0 = 0; j0 < NA; j0 += 1024) {
    int j = j0 + tid;
    uint32_t k = (j < NA) ? skeys[j] : 0;
    bool pass = (j < NA) && ((k >> 16) >= t16);
    uint64_t mask = __ballot(pass);
    int pre = __popcll(mask & ((1ull << lane) - 1ull));
    int wc = __popcll(mask);
    int base = 0;
    if (lane == 0) base = wc ? atomicAdd(&s_cnt, wc) : 0;
    base = __shfl(base, 0);
    if (pass)
      cmp[(size_t)img * NA + base + pre] =
          ((uint64_t)k << 32) | (uint64_t)(0xFFFFFFFFu - (uint32_t)j);
  }
  __syncthreads();
  if (tid == 0) ccount[img] = s_cnt;
}

// ------------------------------------------------- exact rank on top-M set --
__global__ __launch_bounds__(256) void k_rank2(
    const uint64_t* __restrict__ cmp, const int* __restrict__ ccount,
    const float* __restrict__ p0, const float* __restrict__ p1,
    const float* __restrict__ p2, const int* __restrict__ labels,
    const void* __restrict__ hp, const void* __restrict__ wp,
    float4* __restrict__ selbox, float4* __restrict__ selboff,
    float* __restrict__ selscore, int* __restrict__ sellab) {
  __shared__ uint64_t sk[2048];
  int img = blockIdx.y;
  int M = ccount[img]; if (M > NA) M = NA;
  if (blockIdx.x * 256 >= M) return;  // uniform per block
  int c = blockIdx.x * 256 + threadIdx.x;
  uint64_t kc = (c < M) ? cmp[(size_t)img * NA + c] : 0;
  int rank = 0;
  for (int j0 = 0; j0 < M; j0 += 2048) {
    int nchunk = min(2048, M - j0);
    __syncthreads();
    for (int j = threadIdx.x; j < nchunk; j += 256)
      sk[j] = cmp[(size_t)img * NA + j0 + j];
    __syncthreads();
    if (c < M) {
      int j = 0;
      for (; j + 4 <= nchunk; j += 4) {
        rank += (int)(sk[j] > kc) + (int)(sk[j + 1] > kc) +
                (int)(sk[j + 2] > kc) + (int)(sk[j + 3] > kc);
      }
      for (; j < nchunk; ++j) rank += (int)(sk[j] > kc);
    }
  }
  if (c < M && rank < KPRE) {
    int a = (int)(0xFFFFFFFFu - (uint32_t)kc);
    uint32_t uk = (uint32_t)(kc >> 32);
    uint32_t bits = (uk & 0x80000000u) ? (uk & 0x7FFFFFFFu) : ~uk;
    float s = __uint_as_float(bits);
    int lab = labels[img * NA + a];

    int HW, W, m; float stride;
    const float* p = level_ptr(p0, p1, p2, a, HW, W, stride, m);
    const float* base = p + (size_t)img * (4 * NR + NC) * HW + m;
    float d[4];
#pragma unroll
    for (int k = 0; k < 4; ++k) {
      float v[NR]; float mx = -3.4e38f;
#pragma unroll
      for (int r = 0; r < NR; ++r) { v[r] = base[(size_t)(k * NR + r) * HW]; mx = fmaxf(mx, v[r]); }
      float se = 0.f, sn = 0.f;
#pragma unroll
      for (int r = 0; r < NR; ++r) { float e = expf(v[r] - mx); se += e; sn += e * (float)r; }
      d[k] = sn / se * stride;
    }
    int x = m % W, y = m / W;
    float cx = ((float)x + 0.5f) * stride, cy = ((float)y + 0.5f) * stride;
    float hx = read_dim(wp) - 1.f, hy = read_dim(hp) - 1.f;
    float4 bx = make_float4(fminf(fmaxf(cx - d[0], 0.f), hx),
                            fminf(fmaxf(cy - d[1], 0.f), hy),
                            fminf(fmaxf(cx + d[2], 0.f), hx),
                            fminf(fmaxf(cy + d[3], 0.f), hy));
    float off = (float)lab * 4096.0f;  // replicate reference CLS_OFFSET fp math
    int o = img * KPRE + rank;
    selbox[o] = bx;
    selboff[o] = make_float4(bx.x + off, bx.y + off, bx.z + off, bx.w + off);
    selscore[o] = s;
    sellab[o] = lab;
  }
}

// ----------------------------------------------------- IoU suppression bits -
// Output layout TRANSPOSED: rowmask[img][w][i] (w=word 0..15, i=row 0..1023)
// so k_scan's per-chunk staging loads are coalesced.
__global__ __launch_bounds__(256) void k_iou(const float4* __restrict__ selboff,
                                             uint64_t* __restrict__ rowmask) {
  __shared__ float4 bb[KPRE];
  int img = blockIdx.y;
  for (int j = threadIdx.x; j < KPRE; j += 256) bb[j] = selboff[img * KPRE + j];
  __syncthreads();
  int i = blockIdx.x * 16 + (threadIdx.x & 15);
  int w = threadIdx.x >> 4;
  float4 bi = bb[i];
  float ai = (bi.z - bi.x) * (bi.w - bi.y);
  uint64_t bits = 0;
  for (int jj = 0; jj < 64; ++jj) {
    int j = w * 64 + jj;
    float4 bj = bb[j];
    float lx = fmaxf(bi.x, bj.x), ly = fmaxf(bi.y, bj.y);
    float rx = fminf(bi.z, bj.z), ry = fminf(bi.w, bj.w);
    float iw = fmaxf(rx - lx, 0.f), ih = fmaxf(ry - ly, 0.f);
    float inter = iw * ih;
    float aj = (bj.z - bj.x) * (bj.w - bj.y);
    float iou = inter / (ai + aj - inter + 1e-7f);
    bits |= (uint64_t)((iou > IOU_THR) && (j != i)) << jj;
  }
  rowmask[(size_t)img * 16384 + (size_t)w * 1024 + i] = bits;
}

// --------------------------- single-wave barrier-free greedy scan (SALU) ----
// remv: lane t<16 owns word t of the 1024-bit suppressed mask.
// Per chunk c: cur (word c) and vmask are wave-uniform scalars; kept
// candidate ii updates cur via v_readlane from the pre-loaded self-chunk
// words (m). LDS row reads (remv update) are batched off the critical path.
__global__ __launch_bounds__(64) void k_scan(
    const uint64_t* __restrict__ rowmask, const float4* __restrict__ selbox,
    const float* __restrict__ selscore, const int* __restrict__ sellab,
    float* __restrict__ out) {
  __shared__ float lsc[KPRE];
  __shared__ uint64_t buf[2][16 * 65];  // [w*65+ii], pad avoids bank conflicts
  __shared__ int keepidx[MAXDET];
  int img = blockIdx.x, lane = threadIdx.x;
  const uint64_t* g = rowmask + (size_t)img * 16384;

  for (int j = lane; j < KPRE; j += 64) lsc[j] = selscore[img * KPRE + j];

  // stage chunk 0
  {
    uint64_t r0[16];
#pragma unroll
    for (int t = 0; t < 16; ++t) r0[t] = g[t * 1024 + lane];
#pragma unroll
    for (int t = 0; t < 16; ++t) buf[0][t * 65 + lane] = r0[t];
  }
  asm volatile("" ::: "memory");

  uint64_t remv = 0;
  int n = 0;
  for (int c = 0; c < 16; ++c) {
    uint64_t rn[16];
    if (c + 1 < 16) {  // prefetch next chunk (global, overlapped with scan)
#pragma unroll
      for (int t = 0; t < 16; ++t) rn[t] = g[t * 1024 + (c + 1) * 64 + lane];
    }
    const uint64_t* B = buf[c & 1];
    uint64_t m = B[c * 65 + lane];           // self-chunk word of row `lane`
    float sc = lsc[c * 64 + lane];
    uint64_t vmask = __ballot(sc > CONF_T);  // valid (conf-passing) bitmap
    uint64_t cur = readlane64(remv, c);      // suppressed word for this chunk
    uint64_t kmask = 0;
#pragma unroll
    for (int ii = 0; ii < 64; ++ii) {
      if (((vmask >> ii) & 1ull) && !((cur >> ii) & 1ull)) {
        cur |= readlane64(m, ii);
        kmask |= (1ull << ii);
        if (lane == 0 && n < MAXDET) keepidx[n] = c * 64 + ii;
        n++;
      }
    }
    // batch remv update for future chunks (off the serial critical path)
    if (lane < 16) {
      uint64_t km = kmask;
      while (km) {
        int ii2 = __ffsll((unsigned long long)km) - 1;
        km &= km - 1;
        remv |= B[lane * 65 + ii2];
      }
    }
    // stop: last candidate of chunk invalid => all later invalid (sorted)
    if (!((vmask >> 63) & 1ull) || n >= MAXDET) break;
    if (c + 1 < 16) {
#pragma unroll
      for (int t = 0; t < 16; ++t) buf[(c + 1) & 1][t * 65 + lane] = rn[t];
    }
    asm volatile("" ::: "memory");
  }

  // parallel output pass
  asm volatile("" ::: "memory");
  float* ob = out;                        // (B,300,4)
  float* os = out + NB * MAXDET * 4;      // (B,300)
  float* ol = out + NB * MAXDET * 5;      // labels as float
  float* ov = out + NB * MAXDET * 6;      // valid as 0/1 float
  int nk = n < MAXDET ? n : MAXDET;
  for (int s0 = 0; s0 < MAXDET; s0 += 64) {
    int slot = s0 + lane;
    if (slot >= MAXDET) break;
    bool v = slot < nk;
    float4 bx = make_float4(0.f, 0.f, 0.f, 0.f);
    float scv = 0.f, lbv = -1.f;
    if (v) {
      int i = keepidx[slot];
      bx = selbox[img * KPRE + i];
      scv = lsc[i];
      lbv = (float)sellab[img * KPRE + i];
    }
    ((float4*)ob)[img * MAXDET + slot] = bx;
    os[img * MAXDET + slot] = scv;
    ol[img * MAXDET + slot] = lbv;
    ov[img * MAXDET + slot] = v ? 1.0f : 0.0f;
  }
}

// -------------------------------------------------------------- launcher ----
extern "C" void kernel_launch(void* const* d_in, const int* in_sizes, int n_in,
                              void* d_out, int out_size, void* d_ws, size_t ws_size,
                              hipStream_t stream) {
  const float* p0 = (const float*)d_in[0];
  const float* p1 = (const float*)d_in[1];
  const float* p2 = (const float*)d_in[2];
  const void* hp = d_in[3];
  const void* wp = d_in[4];

  char* ws = (char*)d_ws;
  uint32_t* keys     = (uint32_t*)(ws + 0);        // 537600
  int*      labels   = (int*)(ws + 537600);        // 537600
  float4*   selbox   = (float4*)(ws + 1075200);    // 262144
  float4*   selboff  = (float4*)(ws + 1337344);    // 262144
  float*    selscore = (float*)(ws + 1599488);     // 65536
  int*      sellab   = (int*)(ws + 1665024);       // 65536
  int*      ccount   = (int*)(ws + 1730560);       // 64
  uint64_t* cmp      = (uint64_t*)(ws + 1730688);  // 1075200
  uint64_t* rowmask  = (uint64_t*)(ws + 2805888);  // 2097152 [img][w][i]

  k_decode<<<(NB * NA + 255) / 256, 256, 0, stream>>>(p0, p1, p2, keys, labels);
  k_selcomp<<<NB, 1024, 0, stream>>>(keys, cmp, ccount);
  dim3 rg((NA + 255) / 256, NB);
  k_rank2<<<rg, 256, 0, stream>>>(cmp, ccount, p0, p1, p2, labels, hp, wp,
                                  selbox, selboff, selscore, sellab);
  dim3 ig(KPRE / 16, NB);
  k_iou<<<ig, 256, 0, stream>>>(selboff, rowmask);
  k_scan<<<NB, 64, 0, stream>>>(rowmask, selbox, selscore, sellab,
                                (float*)d_out);
}

// Round 5
// 220.122 us; speedup vs baseline: 2.5978x; 1.0242x over previous
//
#include <hip/hip_runtime.h>
#include <stdint.h>

#define NR 16
#define NC 80
#define NA 8400
#define NB 16
#define KPRE 1024
#define MAXDET 300
#define CONF_T 0.25f
#define IOU_THR 0.45f

// Robust scalar read: harness passes python ints most likely as int32; fall
// back to float32 reinterpretation if the int pattern is implausible.
__device__ __forceinline__ float read_dim(const void* p) {
  int iv = *(const int*)p;
  return (iv > 0 && iv < (1 << 20)) ? (float)iv : *(const float*)p;
}

__device__ __forceinline__ const float* level_ptr(const float* p0, const float* p1,
                                                  const float* p2, int a, int& HW,
                                                  int& W, float& stride, int& m) {
  if (a < 6400)      { HW = 6400; W = 80; stride = 8.f;  m = a;        return p0; }
  else if (a < 8000) { HW = 1600; W = 40; stride = 16.f; m = a - 6400; return p1; }
  else               { HW = 400;  W = 20; stride = 32.f; m = a - 8000; return p2; }
}

__device__ __forceinline__ uint64_t readlane64(uint64_t v, int lane) {
  uint32_t lo = (uint32_t)__builtin_amdgcn_readlane((int)(uint32_t)v, lane);
  uint32_t hi = (uint32_t)__builtin_amdgcn_readlane((int)(uint32_t)(v >> 32), lane);
  return ((uint64_t)hi << 32) | lo;
}

// ---------------------------------------------------------------- decode ----
// Full decode for ALL anchors: DFL box + class argmax + sortable key.
// All global reads are lane-coalesced (consecutive m per lane, channel-major
// strides). R4 showed winners-only deferred decode is a losing trade: 64
// scattered cache lines per winner -> 17.5 MB latency-bound gather (42 us).
__global__ __launch_bounds__(256) void k_decode(
    const float* __restrict__ p0, const float* __restrict__ p1,
    const float* __restrict__ p2, const void* __restrict__ hp,
    const void* __restrict__ wp, float4* __restrict__ boxes,
    uint32_t* __restrict__ keys, int* __restrict__ labels) {
  int gid = blockIdx.x * 256 + threadIdx.x;
  if (gid >= NB * NA) return;
  int b = gid / NA, a = gid - b * NA;
  int HW, W, m; float stride;
  const float* p = level_ptr(p0, p1, p2, a, HW, W, stride, m);
  const float* base = p + (size_t)b * (4 * NR + NC) * HW + m;

  // DFL: softmax-expectation over 16 bins for each of l,t,r,b
  float d[4];
#pragma unroll
  for (int k = 0; k < 4; ++k) {
    float v[NR]; float mx = -3.4e38f;
#pragma unroll
    for (int r = 0; r < NR; ++r) { v[r] = base[(size_t)(k * NR + r) * HW]; mx = fmaxf(mx, v[r]); }
    float se = 0.f, sn = 0.f;
#pragma unroll
    for (int r = 0; r < NR; ++r) { float e = expf(v[r] - mx); se += e; sn += e * (float)r; }
    d[k] = sn / se * stride;
  }
  int x = m % W, y = m / W;
  float cx = ((float)x + 0.5f) * stride, cy = ((float)y + 0.5f) * stride;
  float hx = read_dim(wp) - 1.f, hy = read_dim(hp) - 1.f;
  boxes[gid] = make_float4(fminf(fmaxf(cx - d[0], 0.f), hx),
                           fminf(fmaxf(cy - d[1], 0.f), hy),
                           fminf(fmaxf(cx + d[2], 0.f), hx),
                           fminf(fmaxf(cy + d[3], 0.f), hy));

  // class max / argmax on raw logits (sigmoid monotone; strict > = first idx)
  const float* cls = base + (size_t)(4 * NR) * HW;
  float ml = cls[0]; int mc = 0;
#pragma unroll 4
  for (int c = 1; c < NC; ++c) {
    float v = cls[(size_t)c * HW];
    if (v > ml) { ml = v; mc = c; }
  }
  labels[gid] = mc;
  float smax = 1.f / (1.f + expf(-ml));
  float s = smax > CONF_T ? smax : -1.0f;
  uint32_t bt = __float_as_uint(s);
  keys[gid] = (bt & 0x80000000u) ? ~bt : (bt | 0x80000000u);  // order-preserving
}

// ------------------------------- fused radix threshold + compact (per img) --
__global__ __launch_bounds__(1024) void k_selcomp(const uint32_t* __restrict__ keys,
                                                  uint64_t* __restrict__ cmp,
                                                  int* __restrict__ ccount) {
  __shared__ uint32_t skeys[NA];       // 33600 B
  __shared__ uint32_t whist[16][256];  // 16 KB, one hist per wave
  __shared__ uint32_t hsum[256];
  __shared__ uint32_t ssuf[256];
  __shared__ int s_b1, s_rem, s_t16, s_cnt;
  int img = blockIdx.x;
  int tid = threadIdx.x;
  int w = tid >> 6, lane = tid & 63;
  const uint32_t* kb = keys + (size_t)img * NA;
  for (int j = tid; j < NA; j += 1024) skeys[j] = kb[j];
  if (tid == 0) s_cnt = 0;

  // ---- pass 1: digit = key >> 24 ----
  for (int j = tid; j < 16 * 256; j += 1024) ((uint32_t*)whist)[j] = 0;
  __syncthreads();
  for (int j = tid; j < NA; j += 1024) atomicAdd(&whist[w][skeys[j] >> 24], 1u);
  __syncthreads();
  if (tid < 256) { uint32_t s = 0; for (int i = 0; i < 16; ++i) s += whist[i][tid]; hsum[tid] = s; }
  __syncthreads();
  if (tid < 256) { uint32_t s = 0; for (int j = tid; j < 256; ++j) s += hsum[j]; ssuf[tid] = s; }
  __syncthreads();
  if (tid < 256) {
    uint32_t ab = (tid == 255) ? 0u : ssuf[tid + 1];
    if (ssuf[tid] >= KPRE && ab < KPRE) { s_b1 = tid; s_rem = KPRE - (int)ab; }
  }
  __syncthreads();
  int b1 = s_b1, rem = s_rem;
  __syncthreads();

  // ---- pass 2: digit = (key>>16)&0xFF restricted to (key>>24)==b1 ----
  for (int j = tid; j < 16 * 256; j += 1024) ((uint32_t*)whist)[j] = 0;
  __syncthreads();
  for (int j = tid; j < NA; j += 1024) {
    uint32_t k = skeys[j];
    if ((int)(k >> 24) == b1) atomicAdd(&whist[w][(k >> 16) & 0xFF], 1u);
  }
  __syncthreads();
  if (tid < 256) { uint32_t s = 0; for (int i = 0; i < 16; ++i) s += whist[i][tid]; hsum[tid] = s; }
  __syncthreads();
  if (tid < 256) { uint32_t s = 0; for (int j = tid; j < 256; ++j) s += hsum[j]; ssuf[tid] = s; }
  __syncthreads();
  if (tid < 256) {
    int ab = (tid == 255) ? 0 : (int)ssuf[tid + 1];
    if ((int)ssuf[tid] >= rem && ab < rem) s_t16 = (b1 << 8) | tid;
  }
  __syncthreads();
  uint32_t t16 = (uint32_t)s_t16;

  // ---- compact: wave-aggregated slot assignment via one LDS atomic/wave ----
  for (int j0 = 0; j0 < NA; j0 += 1024) {
    int j = j0 + tid;
    uint32_t k = (j < NA) ? skeys[j] : 0;
    bool pass = (j < NA) && ((k >> 16) >= t16);
    uint64_t mask = __ballot(pass);
    int pre = __popcll(mask & ((1ull << lane) - 1ull));
    int wc = __popcll(mask);
    int base = 0;
    if (lane == 0) base = wc ? atomicAdd(&s_cnt, wc) : 0;
    base = __shfl(base, 0);
    if (pass)
      cmp[(size_t)img * NA + base + pre] =
          ((uint64_t)k << 32) | (uint64_t)(0xFFFFFFFFu - (uint32_t)j);
  }
  __syncthreads();
  if (tid == 0) ccount[img] = s_cnt;
}

// ------------------------------------------------- exact rank on top-M set --
// Compacted set == exact top-M keys (upward-closed at bin granularity), so
// local rank == global rank. Winners gather their pre-decoded box (1 float4).
__global__ __launch_bounds__(256) void k_rank2(
    const uint64_t* __restrict__ cmp, const int* __restrict__ ccount,
    const float4* __restrict__ boxes, const int* __restrict__ labels,
    float4* __restrict__ selbox, float4* __restrict__ selboff,
    float* __restrict__ selscore, int* __restrict__ sellab) {
  __shared__ uint64_t sk[2048];
  int img = blockIdx.y;
  int M = ccount[img]; if (M > NA) M = NA;
  if (blockIdx.x * 256 >= M) return;  // uniform per block
  int c = blockIdx.x * 256 + threadIdx.x;
  uint64_t kc = (c < M) ? cmp[(size_t)img * NA + c] : 0;
  int rank = 0;
  for (int j0 = 0; j0 < M; j0 += 2048) {
    int nchunk = min(2048, M - j0);
    __syncthreads();
    for (int j = threadIdx.x; j < nchunk; j += 256)
      sk[j] = cmp[(size_t)img * NA + j0 + j];
    __syncthreads();
    if (c < M) {
      int j = 0;
      for (; j + 4 <= nchunk; j += 4) {
        rank += (int)(sk[j] > kc) + (int)(sk[j + 1] > kc) +
                (int)(sk[j + 2] > kc) + (int)(sk[j + 3] > kc);
      }
      for (; j < nchunk; ++j) rank += (int)(sk[j] > kc);
    }
  }
  if (c < M && rank < KPRE) {
    int a = (int)(0xFFFFFFFFu - (uint32_t)kc);
    uint32_t uk = (uint32_t)(kc >> 32);
    uint32_t bits = (uk & 0x80000000u) ? (uk & 0x7FFFFFFFu) : ~uk;
    float s = __uint_as_float(bits);
    int lab = labels[img * NA + a];
    float4 bx = boxes[img * NA + a];
    float off = (float)lab * 4096.0f;  // replicate reference CLS_OFFSET fp math
    int o = img * KPRE + rank;
    selbox[o] = bx;
    selboff[o] = make_float4(bx.x + off, bx.y + off, bx.z + off, bx.w + off);
    selscore[o] = s;
    sellab[o] = lab;
  }
}

// ----------------------------------------------------- IoU suppression bits -
// Output layout TRANSPOSED: rowmask[img][w][i] (w=word 0..15, i=row 0..1023)
// so k_scan's per-chunk staging loads are coalesced.
__global__ __launch_bounds__(256) void k_iou(const float4* __restrict__ selboff,
                                             uint64_t* __restrict__ rowmask) {
  __shared__ float4 bb[KPRE];
  int img = blockIdx.y;
  for (int j = threadIdx.x; j < KPRE; j += 256) bb[j] = selboff[img * KPRE + j];
  __syncthreads();
  int i = blockIdx.x * 16 + (threadIdx.x & 15);
  int w = threadIdx.x >> 4;
  float4 bi = bb[i];
  float ai = (bi.z - bi.x) * (bi.w - bi.y);
  uint64_t bits = 0;
  for (int jj = 0; jj < 64; ++jj) {
    int j = w * 64 + jj;
    float4 bj = bb[j];
    float lx = fmaxf(bi.x, bj.x), ly = fmaxf(bi.y, bj.y);
    float rx = fminf(bi.z, bj.z), ry = fminf(bi.w, bj.w);
    float iw = fmaxf(rx - lx, 0.f), ih = fmaxf(ry - ly, 0.f);
    float inter = iw * ih;
    float aj = (bj.z - bj.x) * (bj.w - bj.y);
    float iou = inter / (ai + aj - inter + 1e-7f);
    bits |= (uint64_t)((iou > IOU_THR) && (j != i)) << jj;
  }
  rowmask[(size_t)img * 16384 + (size_t)w * 1024 + i] = bits;
}

// --------------------------- single-wave barrier-free greedy scan (SALU) ----
__global__ __launch_bounds__(64) void k_scan(
    const uint64_t* __restrict__ rowmask, const float4* __restrict__ selbox,
    const float* __restrict__ selscore, const int* __restrict__ sellab,
    float* __restrict__ out) {
  __shared__ float lsc[KPRE];
  __shared__ uint64_t buf[2][16 * 65];  // [w*65+ii], pad avoids bank conflicts
  __shared__ int keepidx[MAXDET];
  int img = blockIdx.x, lane = threadIdx.x;
  const uint64_t* g = rowmask + (size_t)img * 16384;

  for (int j = lane; j < KPRE; j += 64) lsc[j] = selscore[img * KPRE + j];

  // stage chunk 0
  {
    uint64_t r0[16];
#pragma unroll
    for (int t = 0; t < 16; ++t) r0[t] = g[t * 1024 + lane];
#pragma unroll
    for (int t = 0; t < 16; ++t) buf[0][t * 65 + lane] = r0[t];
  }
  asm volatile("" ::: "memory");

  uint64_t remv = 0;
  int n = 0;
  for (int c = 0; c < 16; ++c) {
    uint64_t rn[16];
    if (c + 1 < 16) {  // prefetch next chunk (global, overlapped with scan)
#pragma unroll
      for (int t = 0; t < 16; ++t) rn[t] = g[t * 1024 + (c + 1) * 64 + lane];
    }
    const uint64_t* B = buf[c & 1];
    uint64_t m = B[c * 65 + lane];           // self-chunk word of row `lane`
    float sc = lsc[c * 64 + lane];
    uint64_t vmask = __ballot(sc > CONF_T);  // valid (conf-passing) bitmap
    uint64_t cur = readlane64(remv, c);      // suppressed word for this chunk
    uint64_t kmask = 0;
#pragma unroll
    for (int ii = 0; ii < 64; ++ii) {
      if (((vmask >> ii) & 1ull) && !((cur >> ii) & 1ull)) {
        cur |= readlane64(m, ii);
        kmask |= (1ull << ii);
        if (lane == 0 && n < MAXDET) keepidx[n] = c * 64 + ii;
        n++;
      }
    }
    // batch remv update for future chunks (off the serial critical path)
    if (lane < 16) {
      uint64_t km = kmask;
      while (km) {
        int ii2 = __ffsll((unsigned long long)km) - 1;
        km &= km - 1;
        remv |= B[lane * 65 + ii2];
      }
    }
    // stop: last candidate of chunk invalid => all later invalid (sorted)
    if (!((vmask >> 63) & 1ull) || n >= MAXDET) break;
    if (c + 1 < 16) {
#pragma unroll
      for (int t = 0; t < 16; ++t) buf[(c + 1) & 1][t * 65 + lane] = rn[t];
    }
    asm volatile("" ::: "memory");
  }

  // parallel output pass
  asm volatile("" ::: "memory");
  float* ob = out;                        // (B,300,4)
  float* os = out + NB * MAXDET * 4;      // (B,300)
  float* ol = out + NB * MAXDET * 5;      // labels as float
  float* ov = out + NB * MAXDET * 6;      // valid as 0/1 float
  int nk = n < MAXDET ? n : MAXDET;
  for (int s0 = 0; s0 < MAXDET; s0 += 64) {
    int slot = s0 + lane;
    if (slot >= MAXDET) break;
    bool v = slot < nk;
    float4 bx = make_float4(0.f, 0.f, 0.f, 0.f);
    float scv = 0.f, lbv = -1.f;
    if (v) {
      int i = keepidx[slot];
      bx = selbox[img * KPRE + i];
      scv = lsc[i];
      lbv = (float)sellab[img * KPRE + i];
    }
    ((float4*)ob)[img * MAXDET + slot] = bx;
    os[img * MAXDET + slot] = scv;
    ol[img * MAXDET + slot] = lbv;
    ov[img * MAXDET + slot] = v ? 1.0f : 0.0f;
  }
}

// -------------------------------------------------------------- launcher ----
extern "C" void kernel_launch(void* const* d_in, const int* in_sizes, int n_in,
                              void* d_out, int out_size, void* d_ws, size_t ws_size,
                              hipStream_t stream) {
  const float* p0 = (const float*)d_in[0];
  const float* p1 = (const float*)d_in[1];
  const float* p2 = (const float*)d_in[2];
  const void* hp = d_in[3];
  const void* wp = d_in[4];

  // Workspace (~4.96 MB). rowmask ALIASES boxes: boxes is dead after
  // k_rank2's gather; k_iou (writer of rowmask) runs strictly after.
  char* ws = (char*)d_ws;
  float4*   boxes    = (float4*)(ws + 0);          // 2150400
  uint64_t* rowmask  = (uint64_t*)(ws + 0);        // alias: 2097152
  uint32_t* keys     = (uint32_t*)(ws + 2150400);  // 537600
  int*      labels   = (int*)(ws + 2688000);       // 537600
  float4*   selbox   = (float4*)(ws + 3225600);    // 262144
  float4*   selboff  = (float4*)(ws + 3487744);    // 262144
  float*    selscore = (float*)(ws + 3749888);     // 65536
  int*      sellab   = (int*)(ws + 3815424);       // 65536
  int*      ccount   = (int*)(ws + 3880960);       // 64
  uint64_t* cmp      = (uint64_t*)(ws + 3881024);  // 1075200 -> end 4956224

  k_decode<<<(NB * NA + 255) / 256, 256, 0, stream>>>(p0, p1, p2, hp, wp,
                                                      boxes, keys, labels);
  k_selcomp<<<NB, 1024, 0, stream>>>(keys, cmp, ccount);
  dim3 rg((NA + 255) / 256, NB);
  k_rank2<<<rg, 256, 0, stream>>>(cmp, ccount, boxes, labels,
                                  selbox, selboff, selscore, sellab);
  dim3 ig(KPRE / 16, NB);
  k_iou<<<ig, 256, 0, stream>>>(selboff, rowmask);
  k_scan<<<NB, 64, 0, stream>>>(rowmask, selbox, selscore, sellab,
                                (float*)d_out);
}